// Round 16
// baseline (132.530 us; speedup 1.0000x reference)
//
#include <hip/hip_runtime.h>
#include <hip/hip_bf16.h>
#include <math.h>

#define L_SEQ 4096
#define DIM   1024
#define NH    16
#define HD    64

// 0.125 * log2(e): folded into Q so QK^T lands in the exp2 domain pre-scaled.
#define QSCL 0.18033688011112042f

typedef __attribute__((ext_vector_type(4)))  float f32x4;
typedef __attribute__((ext_vector_type(16))) float f32x16;
typedef __attribute__((ext_vector_type(8)))  short s16x8;
typedef __attribute__((ext_vector_type(4)))  short s16x4;
typedef __attribute__((ext_vector_type(4)))  unsigned u32x4;
typedef __attribute__((ext_vector_type(2)))  unsigned u32x2;

#if defined(__has_builtin)
#  if __has_builtin(__builtin_amdgcn_permlane32_swap)
#    define HAVE_PLSWAP 1
#  else
#    define HAVE_PLSWAP 0
#  endif
#else
#  define HAVE_PLSWAP 0
#endif

__device__ __forceinline__ short f2bf(float f) {
  unsigned u = __builtin_bit_cast(unsigned, f);
  u = u + 0x7fffu + ((u >> 16) & 1u);   // RNE
  return (short)(u >> 16);
}

__device__ __forceinline__ float bf2f(short s) {
  return __builtin_bit_cast(float, ((unsigned)(unsigned short)s) << 16);
}

__device__ __forceinline__ unsigned cvt_pk_bf16(float lo, float hi_) {
  unsigned r;
  asm("v_cvt_pk_bf16_f32 %0, %1, %2" : "=v"(r) : "v"(lo), "v"(hi_));
  return r;
}

__device__ __forceinline__ float exp2_fast(float x) {
  float r;
  asm("v_exp_f32 %0, %1" : "=v"(r) : "v"(x));
  return r;
}

__device__ __forceinline__ void gload_lds16(const void* g, void* l) {
  __builtin_amdgcn_global_load_lds(
      (__attribute__((address_space(1))) void*)(g),
      (__attribute__((address_space(3))) void*)(l), 16, 0, 0);
}

// ---------------- fused fp32 -> bf16 convert (x, W_qkv, W_out in one launch) ----
#define CVT_N1 (L_SEQ * DIM / 4)        // 1048576
#define CVT_N2 (3 * DIM * DIM / 4)      // 786432
#define CVT_N3 (DIM * DIM / 4)          // 262144

__global__ __launch_bounds__(256) void cvt_all(const float* __restrict__ x,
                                               const float* __restrict__ Wqkv,
                                               const float* __restrict__ Wout,
                                               short* __restrict__ xb,
                                               short* __restrict__ wqkvb,
                                               short* __restrict__ woutb) {
  int i = blockIdx.x * 256 + threadIdx.x;
  const float* src;
  short* dst;
  int j;
  if (i < CVT_N1)               { src = x;    dst = xb;    j = i; }
  else if (i < CVT_N1 + CVT_N2) { src = Wqkv; dst = wqkvb; j = i - CVT_N1; }
  else                          { src = Wout; dst = woutb; j = i - CVT_N1 - CVT_N2; }
  f32x4 f = *(const f32x4*)(src + j * 4);
  s16x4 o;
  o[0] = f2bf(f[0]); o[1] = f2bf(f[1]); o[2] = f2bf(f[2]); o[3] = f2bf(f[3]);
  *(s16x4*)(dst + j * 4) = o;
}

// ---------------- GEMM: C = A(bf16)[M,K] * B(bf16)[N,K]^T + bias ----------------
// 128x128 tile, 4 waves (2x2 of 64x64), BK=32, mfma_f32_16x16x32_bf16.
// C-frag: col = l&15, row = (l>>4)*4 + reg   (m89-verified)

#define GEMM_MAINLOOP(A_, B_, Kdim)                                            \
  f32x4 acc[4][4];                                                             \
  _Pragma("unroll") for (int m = 0; m < 4; ++m)                                \
  _Pragma("unroll") for (int n = 0; n < 4; ++n) acc[m][n] = (f32x4)0.f;        \
  const short* aptr = A_ + (bm * 128 + w * 16 + (l >> 2)) * (Kdim) + (l & 3) * 8; \
  const short* bptr = B_ + (bn * 128 + w * 16 + (l >> 2)) * (Kdim) + (l & 3) * 8; \
  short* asl = &As[(w * 16) * 32];                                             \
  short* bsl = &Bs[(w * 16) * 32];                                             \
  for (int kk = 0; kk < (Kdim); kk += 32) {                                    \
    gload_lds16(aptr + kk, asl);                                               \
    gload_lds16(aptr + kk + 64 * (Kdim), asl + 64 * 32);                       \
    gload_lds16(bptr + kk, bsl);                                               \
    gload_lds16(bptr + kk + 64 * (Kdim), bsl + 64 * 32);                       \
    __syncthreads();                                                           \
    s16x8 af[4], bfr[4];                                                       \
    _Pragma("unroll") for (int m = 0; m < 4; ++m)                              \
      af[m] = *(const s16x8*)&As[(wr * 64 + m * 16 + lr) * 32 + lg * 8];       \
    _Pragma("unroll") for (int n = 0; n < 4; ++n)                              \
      bfr[n] = *(const s16x8*)&Bs[(wc * 64 + n * 16 + lr) * 32 + lg * 8];      \
    _Pragma("unroll") for (int m = 0; m < 4; ++m)                              \
    _Pragma("unroll") for (int n = 0; n < 4; ++n)                              \
      acc[m][n] = __builtin_amdgcn_mfma_f32_16x16x32_bf16(af[m], bfr[n], acc[m][n], 0, 0, 0); \
    __syncthreads();                                                           \
  }

// Q stored [head][L][64], PRE-SCALED by QSCL. K in A-frag order, V in frag order
// (layout comments as previous rounds). Grid 768, T1 XCD remap.
__global__ __launch_bounds__(256) void gemm_qkv(const short* __restrict__ A,
                                                const short* __restrict__ B,
                                                const float* __restrict__ bias,
                                                short* __restrict__ Qb,
                                                short* __restrict__ Kf,
                                                short* __restrict__ Vf) {
  __shared__ __align__(16) short As[128 * 32];
  __shared__ __align__(16) short Bs[128 * 32];
  const int t = threadIdx.x;
  const int w = t >> 6, l = t & 63;
  const int wr = w >> 1, wc = w & 1;
  const int lr = l & 15, lg = l >> 4;
  const int bid = blockIdx.x;
  const int xcd = bid & 7;
  const int ii = bid >> 3;              // 0..95
  const int bm = xcd * 4 + (ii & 3);    // 0..31
  const int bn = ii >> 2;               // 0..23

  GEMM_MAINLOOP(A, B, DIM)

  const int row0 = bm * 128 + wr * 64;
  const int col0 = bn * 128 + wc * 64;
#pragma unroll
  for (int n = 0; n < 4; ++n) {
    const int col = col0 + n * 16 + lr;
    const float bv = bias[col];
    const int which = col >> 10;
    const int head = (col & 1023) >> 6;
    const int d = col & 63;
    if (which == 0) {
      short* dst = Qb + (head * L_SEQ) * HD + d;
#pragma unroll
      for (int m = 0; m < 4; ++m)
#pragma unroll
        for (int j = 0; j < 4; ++j) {
          const int row = row0 + m * 16 + lg * 4 + j;
          dst[row * HD] = f2bf((acc[m][n][j] + bv) * QSCL);
        }
    } else if (which == 1) {
      const int c = d >> 4, khi = (d >> 3) & 1, e = d & 7;
      short* dst = Kf + head * (L_SEQ * HD);
#pragma unroll
      for (int m = 0; m < 4; ++m)
#pragma unroll
        for (int j = 0; j < 4; ++j) {
          const int row = row0 + m * 16 + lg * 4 + j;
          const int p = row >> 5;
          const int lane = khi * 32 + (row & 31);
          dst[((p * 4 + c) * 64 + lane) * 8 + e] = f2bf(acc[m][n][j] + bv);
        }
    } else {
      const int dh = d >> 5;
      const int dq = d & 31;
      short* dst = Vf + head * (L_SEQ * HD);
#pragma unroll
      for (int m = 0; m < 4; ++m) {
        const int rowb = row0 + m * 16 + lg * 4;
        const int tt = rowb >> 6;
        const int kc = (rowb >> 4) & 3;
        const int khi = (rowb >> 3) & 1;
        const int e0 = rowb & 7;
        s16x4 wv;
#pragma unroll
        for (int j = 0; j < 4; ++j) wv[j] = f2bf(acc[m][n][j] + bv);
        *(s16x4*)&dst[(((tt * 4 + kc) * 2 + dh) * 64 + khi * 32 + dq) * 8 + e0] = wv;
      }
    }
  }
}

// ---------------- out-proj GEMM: 64x64 tile, BK=32. Grid 1024, T1 remap. --------
__global__ __launch_bounds__(256) void gemm_out64(const short* __restrict__ A,
                                                  const short* __restrict__ B,
                                                  const float* __restrict__ bias,
                                                  float* __restrict__ C) {
  __shared__ __align__(16) short As[64 * 32];
  __shared__ __align__(16) short Bs[64 * 32];
  const int t = threadIdx.x;
  const int w = t >> 6, l = t & 63;
  const int wr = w >> 1, wc = w & 1;
  const int lr = l & 15, lg = l >> 4;
  const int bid = blockIdx.x;
  const int xcd = bid & 7;
  const int ii = bid >> 3;              // 0..127
  const int bm = xcd * 8 + (ii & 7);    // 0..63
  const int bn = ii >> 3;               // 0..15

  f32x4 acc[2][2];
#pragma unroll
  for (int m = 0; m < 2; ++m)
#pragma unroll
    for (int n = 0; n < 2; ++n) acc[m][n] = (f32x4)0.f;

  const short* aptr = A + (bm * 64 + (t >> 2)) * DIM + (t & 3) * 8;
  const short* bptr = B + (bn * 64 + (t >> 2)) * DIM + (t & 3) * 8;
  short* asl = &As[t * 8];
  short* bsl = &Bs[t * 8];

  for (int kk = 0; kk < DIM; kk += 32) {
    gload_lds16(aptr + kk, asl);
    gload_lds16(bptr + kk, bsl);
    __syncthreads();
    s16x8 af[2], bfr[2];
#pragma unroll
    for (int m = 0; m < 2; ++m)
      af[m] = *(const s16x8*)&As[(wr * 32 + m * 16 + lr) * 32 + lg * 8];
#pragma unroll
    for (int n = 0; n < 2; ++n)
      bfr[n] = *(const s16x8*)&Bs[(wc * 32 + n * 16 + lr) * 32 + lg * 8];
#pragma unroll
    for (int m = 0; m < 2; ++m)
#pragma unroll
      for (int n = 0; n < 2; ++n)
        acc[m][n] = __builtin_amdgcn_mfma_f32_16x16x32_bf16(af[m], bfr[n], acc[m][n], 0, 0, 0);
    __syncthreads();
  }

  const int row0 = bm * 64 + wr * 32;
  const int col0 = bn * 64 + wc * 32;
#pragma unroll
  for (int n = 0; n < 2; ++n) {
    const int col = col0 + n * 16 + lr;
    const float bv = bias[col];
#pragma unroll
    for (int m = 0; m < 2; ++m)
#pragma unroll
      for (int j = 0; j < 4; ++j) {
        const int row = row0 + m * 16 + lg * 4 + j;
        C[row * DIM + col] = acc[m][n][j] + bv;
      }
  }
}

// ---------------- Flash attention: QBLK=64, LDS-shared K/V, BLOCK SPLIT-K -------
// Grid 2048: block = (head, qt, K-half). Rounds per block <= 32 (was <= 64):
// halves the serial critical path; LDS 32KB -> 4 blocks/CU resident (2x waves).
// Balanced mapping: g=v&15, k=v>>4: half=k>>2, qt=(k&3)*16+(k&4?15-g:g) — any
// CU's 8 units (fixed g, k=0..7) sum to exactly 130 rounds.
// half0 writes RAW (unnormalized) bf16 O into Ob + lsum; half1 writes partial
// buffer PO1 + lsum; merge_o combines: Ob = (O0+O1)/(l0+l1). m=0 reference ->
// plain add. qt=0's half1 is empty and naturally writes zeros.
__global__ __launch_bounds__(256, 4) void attn64s(const short* __restrict__ Qb,
                                                  const short* __restrict__ Kf,
                                                  const short* __restrict__ Vf,
                                                  short* __restrict__ Ob,
                                                  short* __restrict__ PO1,
                                                  float* __restrict__ LS) {
  __shared__ __align__(16) short KV[2][8192];  // 2 x 16KB: [Kev|Kod|Vhalf0|Vhalf1]
  const int bid = blockIdx.x;
  const int xcd = bid & 7;
  const int i = bid >> 3;                       // 0..255
  const int head = (xcd << 1) | (i & 1);        // 2 heads per XCD
  const int v = i >> 1;                         // 0..127
  const int g = v & 15, k = v >> 4;
  const int half = k >> 2;
  const int qt = ((k & 3) << 4) + ((k & 4) ? (15 - g) : g);   // 0..63
  const int q0 = qt * 64;
  const int nr = qt + 1;                        // total 64-key rounds of this qtile
  const int h1 = (qt + 2) >> 1;                 // ceil(nr/2)
  const int r0 = half ? h1 : 0;
  const int r1 = half ? nr : h1;

  const int h = threadIdx.x >> 6;               // wave id 0..3
  const int l = threadIdx.x & 63;
  const int q = l & 31;
  const int hi = l >> 5;
  const int sb = h >> 1;                        // q-subtile 0/1
  const int p = h & 1;                          // kt parity

  const short* Qh = Qb + head * (L_SEQ * HD);
  const short* Kh = Kf + head * (L_SEQ * HD);
  const short* Vh = Vf + head * (L_SEQ * HD);
  const short* gKV = (h < 2) ? Kh : Vh;

  s16x8 qf[4];
#pragma unroll
  for (int c = 0; c < 4; ++c)
    qf[c] = *(const s16x8*)&Qh[(q0 + sb * 32 + q) * HD + c * 16 + hi * 8];

  f32x16 o0 = (f32x16)0.f, o1 = (f32x16)0.f;
  f32x4 lvec = (f32x4)0.f;

  // prologue: stage round r0 (wave h stages region h)
  if (r0 < r1) {
    const short* gsrc = gKV + (2 * r0 + p) * 2048;
    short* lb = &KV[r0 & 1][h * 2048];
#pragma unroll
    for (int c = 0; c < 4; ++c) gload_lds16(gsrc + c * 512 + l * 8, lb + c * 512);
  }
  __syncthreads();

  for (int r = r0; r < r1; ++r) {
    const int buf = r & 1;
    if (r + 1 < r1) {
      const short* gsrc = gKV + (2 * (r + 1) + p) * 2048;
      short* lb = &KV[buf ^ 1][h * 2048];
#pragma unroll
      for (int c = 0; c < 4; ++c) gload_lds16(gsrc + c * 512 + l * 8, lb + c * 512);
    }

    const bool last = (r == nr - 1);
    if (!(h == 1 && last)) {                    // wave1's last tile fully masked
      const short* kb = &KV[buf][p * 2048];
      const short* vb = &KV[buf][(2 + p) * 2048];

      s16x8 kfr[4];
#pragma unroll
      for (int c = 0; c < 4; ++c)
        kfr[c] = *(const s16x8*)&kb[c * 512 + l * 8];

      f32x16 s = (f32x16)0.f;
      __builtin_amdgcn_s_setprio(1);
#pragma unroll
      for (int c = 0; c < 4; ++c)
        s = __builtin_amdgcn_mfma_f32_32x32x16_bf16(kfr[c], qf[c], s, 0, 0, 0);
      __builtin_amdgcn_s_setprio(0);

      // diagonal mask: wave0 (sbA, kt even) / wave3 (sbB, kt odd) on last round
      if (last && (h == 0 || h == 3)) {
        const int qrel = q - hi * 4;
#pragma unroll
        for (int rr = 0; rr < 16; ++rr) {
          const int koff = (rr & 3) + 8 * (rr >> 2);
          if (koff > qrel) s[rr] = -1e30f;
        }
      }

#pragma unroll
      for (int rr = 0; rr < 16; ++rr) s[rr] = exp2_fast(s[rr]);
#pragma unroll
      for (int rr = 0; rr < 16; ++rr) lvec[rr & 3] += s[rr];

#pragma unroll
      for (int cc = 0; cc < 2; ++cc) {
        const int roff = cc * 8;
        const unsigned A = cvt_pk_bf16(s[roff + 0], s[roff + 1]);
        const unsigned B = cvt_pk_bf16(s[roff + 2], s[roff + 3]);
        const unsigned C = cvt_pk_bf16(s[roff + 4], s[roff + 5]);
        const unsigned D = cvt_pk_bf16(s[roff + 6], s[roff + 7]);
        u32x4 pw;
#if HAVE_PLSWAP
        const u32x2 r02 = __builtin_amdgcn_permlane32_swap(A, C, false, false);
        const u32x2 r13 = __builtin_amdgcn_permlane32_swap(B, D, false, false);
        pw[0] = r02[0]; pw[1] = r13[0]; pw[2] = r02[1]; pw[3] = r13[1];
#else
        const unsigned sA = (unsigned)__shfl_xor((int)A, 32, 64);
        const unsigned sB = (unsigned)__shfl_xor((int)B, 32, 64);
        const unsigned sC = (unsigned)__shfl_xor((int)C, 32, 64);
        const unsigned sD = (unsigned)__shfl_xor((int)D, 32, 64);
        pw[0] = hi ? sC : A; pw[1] = hi ? sD : B;
        pw[2] = hi ? C : sA; pw[3] = hi ? D : sB;
#endif
        const s16x8 pf = __builtin_bit_cast(s16x8, pw);
        const s16x8 vf0 = *(const s16x8*)&vb[(cc * 2 + 0) * 512 + l * 8];
        const s16x8 vf1 = *(const s16x8*)&vb[(cc * 2 + 1) * 512 + l * 8];
        __builtin_amdgcn_s_setprio(1);
        o0 = __builtin_amdgcn_mfma_f32_32x32x16_bf16(vf0, pf, o0, 0, 0, 0);
        o1 = __builtin_amdgcn_mfma_f32_32x32x16_bf16(vf1, pf, o1, 0, 0, 0);
        __builtin_amdgcn_s_setprio(0);
      }
    }
    __syncthreads();
  }

  // per-wave denominator: 4 chains + cross-half exchange
  float lsum = (lvec[0] + lvec[1]) + (lvec[2] + lvec[3]);
  lsum += __shfl_xor(lsum, 32, 64);

  // ---- intra-block parity merge (plain add; m=0 reference). Alias staging LDS. --
  unsigned* Ms = (unsigned*)&KV[0][0];
  if (p == 1) {
    unsigned* st = Ms + (sb * 64 + l) * 17;
#pragma unroll
    for (int w2 = 0; w2 < 8; ++w2) st[w2]     = cvt_pk_bf16(o0[2 * w2], o0[2 * w2 + 1]);
#pragma unroll
    for (int w2 = 0; w2 < 8; ++w2) st[8 + w2] = cvt_pk_bf16(o1[2 * w2], o1[2 * w2 + 1]);
    st[16] = __builtin_bit_cast(unsigned, lsum);
  }
  __syncthreads();
  if (p == 0) {
    const unsigned* st = Ms + (sb * 64 + l) * 17;
    lsum += __builtin_bit_cast(float, st[16]);
#pragma unroll
    for (int w2 = 0; w2 < 8; ++w2) {
      const unsigned ua = st[w2];
      o0[2 * w2]     += __builtin_bit_cast(float, ua << 16);
      o0[2 * w2 + 1] += __builtin_bit_cast(float, ua & 0xffff0000u);
      const unsigned ub = st[8 + w2];
      o1[2 * w2]     += __builtin_bit_cast(float, ub << 16);
      o1[2 * w2 + 1] += __builtin_bit_cast(float, ub & 0xffff0000u);
    }
    const int row = sb * 32 + q;                // 0..63 within tile
    const int u = head * 64 + qt;
    LS[(u * 2 + half) * 64 + row] = lsum;       // lanes hi=0/1 duplicate: benign
    // write RAW O (no normalization) — half0 -> Ob slot, half1 -> PO1
    short* dst = (half == 0)
        ? (Ob + (q0 + row) * DIM + head * HD)
        : (PO1 + u * 4096 + row * 64);
#pragma unroll
    for (int dh = 0; dh < 2; ++dh) {
#pragma unroll
      for (int tq = 0; tq < 4; ++tq) {
        s16x4 wv;
#pragma unroll
        for (int jj = 0; jj < 4; ++jj) {
          const int rr = tq * 4 + jj;
          wv[jj] = f2bf((dh == 0) ? o0[rr] : o1[rr]);
        }
        *(s16x4*)&dst[dh * 32 + tq * 8 + hi * 4] = wv;
      }
    }
  }
}

// ---------------- merge the two K-halves: Ob = (Ob + PO1) / (LS0 + LS1) ---------
__global__ __launch_bounds__(256) void merge_o(short* __restrict__ Ob,
                                               const short* __restrict__ PO1,
                                               const float* __restrict__ LS) {
  const int u = blockIdx.x;                     // head*64 + qt
  const int head = u >> 6, qt = u & 63;
  const int t = threadIdx.x;
  const int row = t >> 2;
  const int cs = (t & 3) * 16;
  const float inv = 1.f / (LS[(u * 2) * 64 + row] + LS[(u * 2 + 1) * 64 + row]);
  short* op = Ob + (qt * 64 + row) * DIM + head * HD + cs;
  const short* pp = PO1 + u * 4096 + row * 64 + cs;
  s16x8 a0 = *(const s16x8*)op;
  s16x8 a1 = *(const s16x8*)(op + 8);
  s16x8 b0 = *(const s16x8*)pp;
  s16x8 b1 = *(const s16x8*)(pp + 8);
  s16x8 r0v, r1v;
#pragma unroll
  for (int e = 0; e < 8; ++e) {
    r0v[e] = f2bf((bf2f(a0[e]) + bf2f(b0[e])) * inv);
    r1v[e] = f2bf((bf2f(a1[e]) + bf2f(b1[e])) * inv);
  }
  *(s16x8*)op = r0v;
  *(s16x8*)(op + 8) = r1v;
}

// ---------------- launch ----------------
extern "C" void kernel_launch(void* const* d_in, const int* in_sizes, int n_in,
                              void* d_out, int out_size, void* d_ws, size_t ws_size,
                              hipStream_t stream) {
  const float* x    = (const float*)d_in[0];
  const float* Wqkv = (const float*)d_in[1];
  const float* bqkv = (const float*)d_in[2];
  const float* Wout = (const float*)d_in[3];
  const float* bout = (const float*)d_in[4];
  float* out = (float*)d_out;

  char* ws = (char*)d_ws;
  short* xb    = (short*)(ws);                    // 8 MB  [L][D] bf16 (dead after gemm_qkv)
  short* wqkvb = (short*)(ws + (8u  << 20));      // 6 MB  (dead after gemm_qkv)
  short* woutb = (short*)(ws + (14u << 20));      // 2 MB  [D][D] bf16
  short* Qb    = (short*)(ws + (16u << 20));      // 8 MB  [NH][L][64] (pre-scaled)
  short* Kf    = (short*)(ws + (24u << 20));      // 8 MB  frag-order K
  short* Vf    = (short*)(ws + (32u << 20));      // 8 MB  frag-order V
  short* Ob    = (short*)(ws + (40u << 20));      // 8 MB  [L][D] bf16 (half0 raw -> merged)
  short* PO1   = (short*)(ws);                    // 8 MB  half1 partials (aliases dead xb)
  float* LS    = (float*)(ws + (8u << 20));       // 0.5MB lsums (aliases dead wqkvb)

  cvt_all<<<(CVT_N1 + CVT_N2 + CVT_N3) / 256, 256, 0, stream>>>(x, Wqkv, Wout, xb, wqkvb, woutb);

  gemm_qkv<<<768, 256, 0, stream>>>(xb, wqkvb, bqkv, Qb, Kf, Vf);
  attn64s<<<2048, 256, 0, stream>>>(Qb, Kf, Vf, Ob, PO1, LS);
  merge_o<<<NH * 64, 256, 0, stream>>>(Ob, PO1, LS);
  gemm_out64<<<1024, 256, 0, stream>>>(Ob, woutb, bout, out);
}

// Round 17
// 126.162 us; speedup vs baseline: 1.0505x; 1.0505x over previous
//
#include <hip/hip_runtime.h>
#include <hip/hip_bf16.h>
#include <math.h>

#define L_SEQ 4096
#define DIM   1024
#define NH    16
#define HD    64

// 0.125 * log2(e): folded into Q so QK^T lands in the exp2 domain pre-scaled.
#define QSCL 0.18033688011112042f

typedef __attribute__((ext_vector_type(4)))  float f32x4;
typedef __attribute__((ext_vector_type(16))) float f32x16;
typedef __attribute__((ext_vector_type(8)))  short s16x8;
typedef __attribute__((ext_vector_type(4)))  short s16x4;
typedef __attribute__((ext_vector_type(4)))  unsigned u32x4;
typedef __attribute__((ext_vector_type(2)))  unsigned u32x2;

#if defined(__has_builtin)
#  if __has_builtin(__builtin_amdgcn_permlane32_swap)
#    define HAVE_PLSWAP 1
#  else
#    define HAVE_PLSWAP 0
#  endif
#else
#  define HAVE_PLSWAP 0
#endif

__device__ __forceinline__ short f2bf(float f) {
  unsigned u = __builtin_bit_cast(unsigned, f);
  u = u + 0x7fffu + ((u >> 16) & 1u);   // RNE
  return (short)(u >> 16);
}

__device__ __forceinline__ unsigned cvt_pk_bf16(float lo, float hi_) {
  unsigned r;
  asm("v_cvt_pk_bf16_f32 %0, %1, %2" : "=v"(r) : "v"(lo), "v"(hi_));
  return r;
}

__device__ __forceinline__ float exp2_fast(float x) {
  float r;
  asm("v_exp_f32 %0, %1" : "=v"(r) : "v"(x));
  return r;
}

__device__ __forceinline__ void gload_lds16(const void* g, void* l) {
  __builtin_amdgcn_global_load_lds(
      (__attribute__((address_space(1))) void*)(g),
      (__attribute__((address_space(3))) void*)(l), 16, 0, 0);
}

// ---------------- fused fp32 -> bf16 convert (x, W_qkv, W_out in one launch) ----
#define CVT_N1 (L_SEQ * DIM / 4)        // 1048576
#define CVT_N2 (3 * DIM * DIM / 4)      // 786432
#define CVT_N3 (DIM * DIM / 4)          // 262144

__global__ __launch_bounds__(256) void cvt_all(const float* __restrict__ x,
                                               const float* __restrict__ Wqkv,
                                               const float* __restrict__ Wout,
                                               short* __restrict__ xb,
                                               short* __restrict__ wqkvb,
                                               short* __restrict__ woutb) {
  int i = blockIdx.x * 256 + threadIdx.x;
  const float* src;
  short* dst;
  int j;
  if (i < CVT_N1)               { src = x;    dst = xb;    j = i; }
  else if (i < CVT_N1 + CVT_N2) { src = Wqkv; dst = wqkvb; j = i - CVT_N1; }
  else                          { src = Wout; dst = woutb; j = i - CVT_N1 - CVT_N2; }
  f32x4 f = *(const f32x4*)(src + j * 4);
  s16x4 o;
  o[0] = f2bf(f[0]); o[1] = f2bf(f[1]); o[2] = f2bf(f[2]); o[3] = f2bf(f[3]);
  *(s16x4*)(dst + j * 4) = o;
}

// ---------------- GEMM mainloops: 128x128 tile, 4 waves, BK=32 ------------------
// Normal:  acc[m][n] = mfma(af[m], bfr[n]) -> C[row=x, col=W]
//   C-frag: col = l&15 (W-col), row = (l>>4)*4 + reg (x-row)  [m89-verified]
// Swapped: acc[m][n] = mfma(bfr[n], af[m]) -> C^T: thread holds 4 CONSECUTIVE
//   W-cols (n*16+lg*4+j) at ONE x-row (m*16+lr) -> vectorized epilogue stores.

#define GEMM_STAGE_AND_FRAGS(A_, B_, Kdim)                                     \
  const short* aptr = A_ + (bm * 128 + w * 16 + (l >> 2)) * (Kdim) + (l & 3) * 8; \
  const short* bptr = B_ + (bn * 128 + w * 16 + (l >> 2)) * (Kdim) + (l & 3) * 8; \
  short* asl = &As[(w * 16) * 32];                                             \
  short* bsl = &Bs[(w * 16) * 32];

#define GEMM_KSTEP(Kdim)                                                       \
    gload_lds16(aptr + kk, asl);                                               \
    gload_lds16(aptr + kk + 64 * (Kdim), asl + 64 * 32);                       \
    gload_lds16(bptr + kk, bsl);                                               \
    gload_lds16(bptr + kk + 64 * (Kdim), bsl + 64 * 32);                       \
    __syncthreads();                                                           \
    s16x8 af[4], bfr[4];                                                       \
    _Pragma("unroll") for (int m = 0; m < 4; ++m)                              \
      af[m] = *(const s16x8*)&As[(wr * 64 + m * 16 + lr) * 32 + lg * 8];       \
    _Pragma("unroll") for (int n = 0; n < 4; ++n)                              \
      bfr[n] = *(const s16x8*)&Bs[(wc * 64 + n * 16 + lr) * 32 + lg * 8];

// ---------------- Q/K projection GEMM (swapped C^T, vectorized epilogue) --------
// Covers W_qkv rows 0..2047 (Q and K). Grid 512: xcd owns bm in [4x,4x+4) x bn 0..15.
__global__ __launch_bounds__(256) void gemm_qk(const short* __restrict__ A,
                                               const short* __restrict__ B,
                                               const float* __restrict__ bias,
                                               short* __restrict__ Qb,
                                               short* __restrict__ Kf) {
  __shared__ __align__(16) short As[128 * 32];
  __shared__ __align__(16) short Bs[128 * 32];
  const int t = threadIdx.x;
  const int w = t >> 6, l = t & 63;
  const int wr = w >> 1, wc = w & 1;
  const int lr = l & 15, lg = l >> 4;
  const int bid = blockIdx.x;
  const int xcd = bid & 7;
  const int ii = bid >> 3;              // 0..63
  const int bm = xcd * 4 + (ii & 3);    // 0..31
  const int bn = ii >> 2;               // 0..15 (Q: 0..7, K: 8..15)

  f32x4 acc[4][4];
#pragma unroll
  for (int m = 0; m < 4; ++m)
#pragma unroll
    for (int n = 0; n < 4; ++n) acc[m][n] = (f32x4)0.f;

  GEMM_STAGE_AND_FRAGS(A, B, DIM)
  for (int kk = 0; kk < DIM; kk += 32) {
    GEMM_KSTEP(DIM)
#pragma unroll
    for (int m = 0; m < 4; ++m)
#pragma unroll
      for (int n = 0; n < 4; ++n)
        acc[m][n] = __builtin_amdgcn_mfma_f32_16x16x32_bf16(bfr[n], af[m], acc[m][n], 0, 0, 0);
    __syncthreads();
  }

  // C^T epilogue: acc[m][n][j] = C[x-row = bm*128+wr*64+m*16+lr]
  //                              [W-col = bn*128+wc*64+n*16+lg*4+j]
  const int row0x = bm * 128 + wr * 64;
#pragma unroll
  for (int n = 0; n < 4; ++n) {
    const int colb = bn * 128 + wc * 64 + n * 16 + lg * 4;   // 4-aligned
    const f32x4 bv4 = *(const f32x4*)&bias[colb];
    const int which = colb >> 10;                            // 0=Q, 1=K (block-uniform)
    const int head = (colb & 1023) >> 6;
    const int d0 = colb & 63;                                // 4-aligned
    if (which == 0) {
      short* dst = Qb + head * (L_SEQ * HD);
#pragma unroll
      for (int m = 0; m < 4; ++m) {
        const int xrow = row0x + m * 16 + lr;
        s16x4 wv;
#pragma unroll
        for (int j = 0; j < 4; ++j) wv[j] = f2bf((acc[m][n][j] + bv4[j]) * QSCL);
        *(s16x4*)&dst[xrow * HD + d0] = wv;
      }
    } else {
      short* dst = Kf + head * (L_SEQ * HD);
      const int c = d0 >> 4, khi = (d0 >> 3) & 1, e0 = d0 & 7;  // e0 in {0,4}
#pragma unroll
      for (int m = 0; m < 4; ++m) {
        const int xrow = row0x + m * 16 + lr;
        const int p = xrow >> 5;
        const int lane = khi * 32 + (xrow & 31);
        s16x4 wv;
#pragma unroll
        for (int j = 0; j < 4; ++j) wv[j] = f2bf(acc[m][n][j] + bv4[j]);
        *(s16x4*)&dst[((p * 4 + c) * 64 + lane) * 8 + e0] = wv;
      }
    }
  }
}

// ---------------- V projection GEMM (normal orientation, frag-order stores) -----
// Covers W_qkv rows 2048..3071. Grid 256: xcd owns bm in [4x,4x+4) x bn 16..23.
// V frag order: Vf[head][t=row/64][kc=(row/16)&3][dh=d/32][lane][8],
//   lane = ((row>>3)&1)*32 + (d&31), elem = row&7.
__global__ __launch_bounds__(256) void gemm_v(const short* __restrict__ A,
                                              const short* __restrict__ B,
                                              const float* __restrict__ bias,
                                              short* __restrict__ Vf) {
  __shared__ __align__(16) short As[128 * 32];
  __shared__ __align__(16) short Bs[128 * 32];
  const int t = threadIdx.x;
  const int w = t >> 6, l = t & 63;
  const int wr = w >> 1, wc = w & 1;
  const int lr = l & 15, lg = l >> 4;
  const int bid = blockIdx.x;
  const int xcd = bid & 7;
  const int ii = bid >> 3;              // 0..31
  const int bm = xcd * 4 + (ii & 3);    // 0..31
  const int bn = 16 + (ii >> 2);        // 16..23

  f32x4 acc[4][4];
#pragma unroll
  for (int m = 0; m < 4; ++m)
#pragma unroll
    for (int n = 0; n < 4; ++n) acc[m][n] = (f32x4)0.f;

  GEMM_STAGE_AND_FRAGS(A, B, DIM)
  for (int kk = 0; kk < DIM; kk += 32) {
    GEMM_KSTEP(DIM)
#pragma unroll
    for (int m = 0; m < 4; ++m)
#pragma unroll
      for (int n = 0; n < 4; ++n)
        acc[m][n] = __builtin_amdgcn_mfma_f32_16x16x32_bf16(af[m], bfr[n], acc[m][n], 0, 0, 0);
    __syncthreads();
  }

  const int row0 = bm * 128 + wr * 64;
  const int col0 = bn * 128 + wc * 64;
#pragma unroll
  for (int n = 0; n < 4; ++n) {
    const int col = col0 + n * 16 + lr;
    const float bv = bias[col];
    const int head = (col & 1023) >> 6;
    const int d = col & 63;
    const int dh = d >> 5;
    const int dq = d & 31;
    short* dst = Vf + head * (L_SEQ * HD);
#pragma unroll
    for (int m = 0; m < 4; ++m) {
      const int rowb = row0 + m * 16 + lg * 4;
      const int tt = rowb >> 6;
      const int kc = (rowb >> 4) & 3;
      const int khi = (rowb >> 3) & 1;
      const int e0 = rowb & 7;
      s16x4 wv;
#pragma unroll
      for (int j = 0; j < 4; ++j) wv[j] = f2bf(acc[m][n][j] + bv);
      *(s16x4*)&dst[(((tt * 4 + kc) * 2 + dh) * 64 + khi * 32 + dq) * 8 + e0] = wv;
    }
  }
}

// ---------------- out-proj GEMM: 64x64 tile, BK=32. Grid 1024, T1 remap. --------
__global__ __launch_bounds__(256) void gemm_out64(const short* __restrict__ A,
                                                  const short* __restrict__ B,
                                                  const float* __restrict__ bias,
                                                  float* __restrict__ C) {
  __shared__ __align__(16) short As[64 * 32];
  __shared__ __align__(16) short Bs[64 * 32];
  const int t = threadIdx.x;
  const int w = t >> 6, l = t & 63;
  const int wr = w >> 1, wc = w & 1;
  const int lr = l & 15, lg = l >> 4;
  const int bid = blockIdx.x;
  const int xcd = bid & 7;
  const int ii = bid >> 3;              // 0..127
  const int bm = xcd * 8 + (ii & 7);    // 0..63
  const int bn = ii >> 3;               // 0..15

  f32x4 acc[2][2];
#pragma unroll
  for (int m = 0; m < 2; ++m)
#pragma unroll
    for (int n = 0; n < 2; ++n) acc[m][n] = (f32x4)0.f;

  const short* aptr = A + (bm * 64 + (t >> 2)) * DIM + (t & 3) * 8;
  const short* bptr = B + (bn * 64 + (t >> 2)) * DIM + (t & 3) * 8;
  short* asl = &As[t * 8];
  short* bsl = &Bs[t * 8];

  for (int kk = 0; kk < DIM; kk += 32) {
    gload_lds16(aptr + kk, asl);
    gload_lds16(bptr + kk, bsl);
    __syncthreads();
    s16x8 af[2], bfr[2];
#pragma unroll
    for (int m = 0; m < 2; ++m)
      af[m] = *(const s16x8*)&As[(wr * 32 + m * 16 + lr) * 32 + lg * 8];
#pragma unroll
    for (int n = 0; n < 2; ++n)
      bfr[n] = *(const s16x8*)&Bs[(wc * 32 + n * 16 + lr) * 32 + lg * 8];
#pragma unroll
    for (int m = 0; m < 2; ++m)
#pragma unroll
      for (int n = 0; n < 2; ++n)
        acc[m][n] = __builtin_amdgcn_mfma_f32_16x16x32_bf16(af[m], bfr[n], acc[m][n], 0, 0, 0);
    __syncthreads();
  }

  const int row0 = bm * 64 + wr * 32;
  const int col0 = bn * 64 + wc * 32;
#pragma unroll
  for (int n = 0; n < 2; ++n) {
    const int col = col0 + n * 16 + lr;
    const float bv = bias[col];
#pragma unroll
    for (int m = 0; m < 2; ++m)
#pragma unroll
      for (int j = 0; j < 4; ++j) {
        const int row = row0 + m * 16 + lg * 4 + j;
        C[row * DIM + col] = acc[m][n][j] + bv;
      }
  }
}

// ---------------- Flash attention: QBLK=64, LDS-shared K/V (round-15, 53us) -----
// Block = one 64-row qtile, 4 waves: (q-subtile sb = h>>1) x (kt parity p = h&1).
// Per 64-key round: block stages K(2 tiles)+V(2 tiles) = 16KB ONCE into
// double-buffered LDS; both q-subtile waves consume from LDS (halves L2 bytes).
// Fixed softmax reference m=0; pairwise merge (waves 1,3 -> 0,2) via aliased LDS.
// CU balance: qt = (j<32)? 63-j : j-32. Grid 1024; xcd=bid&7 owns 2 heads.
__global__ __launch_bounds__(256, 4) void attn64(const short* __restrict__ Qb,
                                                 const short* __restrict__ Kf,
                                                 const short* __restrict__ Vf,
                                                 short* __restrict__ Ob) {
  __shared__ __align__(16) short KV[2][8192];  // 2 x 16KB: [Kev|Kod|Vev|Vod] x 4KB
  const int bid = blockIdx.x;
  const int xcd = bid & 7;
  const int i = bid >> 3;                       // 0..127
  const int head = (xcd << 1) | (i >> 6);       // 2 heads per XCD
  const int j = i & 63;
  const int qt = (j < 32) ? (63 - j) : (j - 32);  // balanced heavy/light per CU
  const int q0 = qt * 64;
  const int h = threadIdx.x >> 6;               // wave id 0..3
  const int l = threadIdx.x & 63;
  const int q = l & 31;
  const int hi = l >> 5;
  const int sb = h >> 1;                        // q-subtile 0/1
  const int p = h & 1;                          // kt parity

  const short* Qh = Qb + head * (L_SEQ * HD);
  const short* Kh = Kf + head * (L_SEQ * HD);
  const short* Vh = Vf + head * (L_SEQ * HD);
  const short* gKV = (h < 2) ? Kh : Vh;         // this wave's staging source

  s16x8 qf[4];
#pragma unroll
  for (int c = 0; c < 4; ++c)
    qf[c] = *(const s16x8*)&Qh[(q0 + sb * 32 + q) * HD + c * 16 + hi * 8];

  f32x16 o0 = (f32x16)0.f, o1 = (f32x16)0.f;
  f32x4 lvec = (f32x4)0.f;

  const int nr = qt + 1;                        // 64-key rounds

  // prologue: stage round 0 (wave h stages region h: kt = p of K or V)
  {
    const short* gsrc = gKV + p * 2048;
    short* lb = &KV[0][h * 2048];
#pragma unroll
    for (int c = 0; c < 4; ++c) gload_lds16(gsrc + c * 512 + l * 8, lb + c * 512);
  }
  __syncthreads();

  for (int r = 0; r < nr; ++r) {
    const int buf = r & 1;
    if (r + 1 < nr) {                           // stage next round into other buf
      const short* gsrc = gKV + (2 * (r + 1) + p) * 2048;
      short* lb = &KV[buf ^ 1][h * 2048];
#pragma unroll
      for (int c = 0; c < 4; ++c) gload_lds16(gsrc + c * 512 + l * 8, lb + c * 512);
    }

    const bool last = (r == nr - 1);
    if (!(h == 1 && last)) {                    // wave1's last tile fully masked
      const short* kb = &KV[buf][p * 2048];
      const short* vb = &KV[buf][(2 + p) * 2048];

      s16x8 kfr[4];
#pragma unroll
      for (int c = 0; c < 4; ++c)
        kfr[c] = *(const s16x8*)&kb[c * 512 + l * 8];

      f32x16 s = (f32x16)0.f;
      __builtin_amdgcn_s_setprio(1);
#pragma unroll
      for (int c = 0; c < 4; ++c)
        s = __builtin_amdgcn_mfma_f32_32x32x16_bf16(kfr[c], qf[c], s, 0, 0, 0);
      __builtin_amdgcn_s_setprio(0);

      // diagonal mask: wave0 (sbA, kt even) / wave3 (sbB, kt odd) on last round
      if (last && (h == 0 || h == 3)) {
        const int qrel = q - hi * 4;
#pragma unroll
        for (int rr = 0; rr < 16; ++rr) {
          const int koff = (rr & 3) + 8 * (rr >> 2);
          if (koff > qrel) s[rr] = -1e30f;
        }
      }

#pragma unroll
      for (int rr = 0; rr < 16; ++rr) s[rr] = exp2_fast(s[rr]);
#pragma unroll
      for (int rr = 0; rr < 16; ++rr) lvec[rr & 3] += s[rr];

#pragma unroll
      for (int cc = 0; cc < 2; ++cc) {
        const int roff = cc * 8;
        const unsigned A = cvt_pk_bf16(s[roff + 0], s[roff + 1]);
        const unsigned B = cvt_pk_bf16(s[roff + 2], s[roff + 3]);
        const unsigned C = cvt_pk_bf16(s[roff + 4], s[roff + 5]);
        const unsigned D = cvt_pk_bf16(s[roff + 6], s[roff + 7]);
        u32x4 pw;
#if HAVE_PLSWAP
        const u32x2 r02 = __builtin_amdgcn_permlane32_swap(A, C, false, false);
        const u32x2 r13 = __builtin_amdgcn_permlane32_swap(B, D, false, false);
        pw[0] = r02[0]; pw[1] = r13[0]; pw[2] = r02[1]; pw[3] = r13[1];
#else
        const unsigned sA = (unsigned)__shfl_xor((int)A, 32, 64);
        const unsigned sB = (unsigned)__shfl_xor((int)B, 32, 64);
        const unsigned sC = (unsigned)__shfl_xor((int)C, 32, 64);
        const unsigned sD = (unsigned)__shfl_xor((int)D, 32, 64);
        pw[0] = hi ? sC : A; pw[1] = hi ? sD : B;
        pw[2] = hi ? C : sA; pw[3] = hi ? D : sB;
#endif
        const s16x8 pf = __builtin_bit_cast(s16x8, pw);
        const s16x8 vf0 = *(const s16x8*)&vb[(cc * 2 + 0) * 512 + l * 8];
        const s16x8 vf1 = *(const s16x8*)&vb[(cc * 2 + 1) * 512 + l * 8];
        __builtin_amdgcn_s_setprio(1);
        o0 = __builtin_amdgcn_mfma_f32_32x32x16_bf16(vf0, pf, o0, 0, 0, 0);
        o1 = __builtin_amdgcn_mfma_f32_32x32x16_bf16(vf1, pf, o1, 0, 0, 0);
        __builtin_amdgcn_s_setprio(0);
      }
    }
    __syncthreads();   // drains this wave's gloads (vmcnt0) + orders buffers
  }

  // per-wave denominator: 4 chains + cross-half exchange
  float lsum = (lvec[0] + lvec[1]) + (lvec[2] + lvec[3]);
  lsum += __shfl_xor(lsum, 32, 64);

  // ---- pairwise merge (same m=0 reference -> plain add). Alias staging LDS. ----
  unsigned* Ms = (unsigned*)&KV[0][0];          // [2][64][17]
  if (p == 1) {                                 // waves 1,3 write partials
    unsigned* st = Ms + (sb * 64 + l) * 17;
#pragma unroll
    for (int w2 = 0; w2 < 8; ++w2) st[w2]     = cvt_pk_bf16(o0[2 * w2], o0[2 * w2 + 1]);
#pragma unroll
    for (int w2 = 0; w2 < 8; ++w2) st[8 + w2] = cvt_pk_bf16(o1[2 * w2], o1[2 * w2 + 1]);
    st[16] = __builtin_bit_cast(unsigned, lsum);
  }
  __syncthreads();
  if (p == 0) {                                 // waves 0,2 combine & write
    const unsigned* st = Ms + (sb * 64 + l) * 17;
    lsum += __builtin_bit_cast(float, st[16]);
#pragma unroll
    for (int w2 = 0; w2 < 8; ++w2) {
      const unsigned ua = st[w2];
      o0[2 * w2]     += __builtin_bit_cast(float, ua << 16);
      o0[2 * w2 + 1] += __builtin_bit_cast(float, ua & 0xffff0000u);
      const unsigned ub = st[8 + w2];
      o1[2 * w2]     += __builtin_bit_cast(float, ub << 16);
      o1[2 * w2 + 1] += __builtin_bit_cast(float, ub & 0xffff0000u);
    }
    const float inv = 1.f / lsum;
    const int orow = q0 + sb * 32 + q;
#pragma unroll
    for (int dh = 0; dh < 2; ++dh) {
#pragma unroll
      for (int tq = 0; tq < 4; ++tq) {
        s16x4 wv;
#pragma unroll
        for (int jj = 0; jj < 4; ++jj) {
          const int rr = tq * 4 + jj;
          const float ov = (dh == 0) ? o0[rr] : o1[rr];
          wv[jj] = f2bf(ov * inv);
        }
        *(s16x4*)&Ob[orow * DIM + head * HD + dh * 32 + tq * 8 + hi * 4] = wv;
      }
    }
  }
}

// ---------------- launch ----------------
extern "C" void kernel_launch(void* const* d_in, const int* in_sizes, int n_in,
                              void* d_out, int out_size, void* d_ws, size_t ws_size,
                              hipStream_t stream) {
  const float* x    = (const float*)d_in[0];
  const float* Wqkv = (const float*)d_in[1];
  const float* bqkv = (const float*)d_in[2];
  const float* Wout = (const float*)d_in[3];
  const float* bout = (const float*)d_in[4];
  float* out = (float*)d_out;

  char* ws = (char*)d_ws;
  short* xb    = (short*)(ws);                    // 8 MB  [L][D] bf16
  short* wqkvb = (short*)(ws + (8u  << 20));      // 6 MB  [3D][D] bf16
  short* woutb = (short*)(ws + (14u << 20));      // 2 MB  [D][D] bf16
  short* Qb    = (short*)(ws + (16u << 20));      // 8 MB  [NH][L][64] (pre-scaled)
  short* Kf    = (short*)(ws + (24u << 20));      // 8 MB  frag-order K
  short* Vf    = (short*)(ws + (32u << 20));      // 8 MB  frag-order V
  short* Ob    = (short*)(ws + (40u << 20));      // 8 MB  [L][D] bf16

  cvt_all<<<(CVT_N1 + CVT_N2 + CVT_N3) / 256, 256, 0, stream>>>(x, Wqkv, Wout, xb, wqkvb, woutb);

  gemm_qk<<<512, 256, 0, stream>>>(xb, wqkvb, bqkv, Qb, Kf);
  gemm_v<<<256, 256, 0, stream>>>(xb, wqkvb, bqkv, Vf);
  attn64<<<1024, 256, 0, stream>>>(Qb, Kf, Vf, Ob);
  gemm_out64<<<1024, 256, 0, stream>>>(Ob, woutb, bout, out);
}

// Round 18
// 123.998 us; speedup vs baseline: 1.0688x; 1.0174x over previous
//
#include <hip/hip_runtime.h>
#include <hip/hip_bf16.h>
#include <math.h>

#define L_SEQ 4096
#define DIM   1024
#define NH    16
#define HD    64

// 0.125 * log2(e): folded into Q so QK^T lands in the exp2 domain pre-scaled.
#define QSCL 0.18033688011112042f

typedef __attribute__((ext_vector_type(4)))  float f32x4;
typedef __attribute__((ext_vector_type(16))) float f32x16;
typedef __attribute__((ext_vector_type(8)))  short s16x8;
typedef __attribute__((ext_vector_type(4)))  short s16x4;
typedef __attribute__((ext_vector_type(4)))  unsigned u32x4;
typedef __attribute__((ext_vector_type(2)))  unsigned u32x2;

#if defined(__has_builtin)
#  if __has_builtin(__builtin_amdgcn_permlane32_swap)
#    define HAVE_PLSWAP 1
#  else
#    define HAVE_PLSWAP 0
#  endif
#else
#  define HAVE_PLSWAP 0
#endif

__device__ __forceinline__ short f2bf(float f) {
  unsigned u = __builtin_bit_cast(unsigned, f);
  u = u + 0x7fffu + ((u >> 16) & 1u);   // RNE
  return (short)(u >> 16);
}

__device__ __forceinline__ unsigned cvt_pk_bf16(float lo, float hi_) {
  unsigned r;
  asm("v_cvt_pk_bf16_f32 %0, %1, %2" : "=v"(r) : "v"(lo), "v"(hi_));
  return r;
}

__device__ __forceinline__ float exp2_fast(float x) {
  float r;
  asm("v_exp_f32 %0, %1" : "=v"(r) : "v"(x));
  return r;
}

__device__ __forceinline__ void gload_lds16(const void* g, void* l) {
  __builtin_amdgcn_global_load_lds(
      (__attribute__((address_space(1))) void*)(g),
      (__attribute__((address_space(3))) void*)(l), 16, 0, 0);
}

// ---------------- fused fp32 -> bf16 convert (x, W_qkv, W_out in one launch) ----
#define CVT_N1 (L_SEQ * DIM / 4)        // 1048576
#define CVT_N2 (3 * DIM * DIM / 4)      // 786432
#define CVT_N3 (DIM * DIM / 4)          // 262144

__global__ __launch_bounds__(256) void cvt_all(const float* __restrict__ x,
                                               const float* __restrict__ Wqkv,
                                               const float* __restrict__ Wout,
                                               short* __restrict__ xb,
                                               short* __restrict__ wqkvb,
                                               short* __restrict__ woutb) {
  int i = blockIdx.x * 256 + threadIdx.x;
  const float* src;
  short* dst;
  int j;
  if (i < CVT_N1)               { src = x;    dst = xb;    j = i; }
  else if (i < CVT_N1 + CVT_N2) { src = Wqkv; dst = wqkvb; j = i - CVT_N1; }
  else                          { src = Wout; dst = woutb; j = i - CVT_N1 - CVT_N2; }
  f32x4 f = *(const f32x4*)(src + j * 4);
  s16x4 o;
  o[0] = f2bf(f[0]); o[1] = f2bf(f[1]); o[2] = f2bf(f[2]); o[3] = f2bf(f[3]);
  *(s16x4*)(dst + j * 4) = o;
}

// ---------------- merged QKV projection GEMM: 64x128 tile, 6 blocks/CU ----------
// Grid 1536 (64 bm x 24 bn), T1 remap: XCD x owns bm in [8x,8x+8) x all bn.
// 4 waves; wave w owns output strip [64 x 32] at n-base w*32. BK=32.
// acc[m 0..3][n 0..1] (32 AGPR). Per K-iter: 3 gload_lds + 8 MFMA.
// Staging (rule #21, wave-uniform LDS base + lane*16B):
//   A: wave w stages rows w*16+(l>>2) (covers 0..63), col8 = l&3 -> As 4KB
//   B: wave w stages rows w*16+(l>>2) and +64 (covers 0..127)   -> Bs 8KB
// Q/K (bn 0..15): SWAPPED mfma(bfr, af) -> C^T, thread holds 4 consecutive
//   W-cols at one x-row -> vectorized stores (verified round 17).
// V (bn 16..23): normal orientation, frag-order s16x4 stores.
__global__ __launch_bounds__(256) void gemm_qkv64(const short* __restrict__ A,
                                                  const short* __restrict__ B,
                                                  const float* __restrict__ bias,
                                                  short* __restrict__ Qb,
                                                  short* __restrict__ Kf,
                                                  short* __restrict__ Vf) {
  __shared__ __align__(16) short As[64 * 32];    // 4 KB
  __shared__ __align__(16) short Bs[128 * 32];   // 8 KB
  const int t = threadIdx.x;
  const int w = t >> 6, l = t & 63;
  const int lr = l & 15, lg = l >> 4;
  const int bid = blockIdx.x;
  const int xcd = bid & 7;
  const int ii = bid >> 3;              // 0..191
  const int bm = xcd * 8 + (ii & 7);    // 0..63
  const int bn = ii >> 3;               // 0..23
  const bool isV = (bn >= 16);

  f32x4 acc[4][2];
#pragma unroll
  for (int m = 0; m < 4; ++m)
#pragma unroll
    for (int n = 0; n < 2; ++n) acc[m][n] = (f32x4)0.f;

  const short* aptr = A + (bm * 64 + w * 16 + (l >> 2)) * DIM + (l & 3) * 8;
  const short* bptr = B + (bn * 128 + w * 16 + (l >> 2)) * DIM + (l & 3) * 8;
  short* asl = &As[(w * 16) * 32];
  short* bsl = &Bs[(w * 16) * 32];

  for (int kk = 0; kk < DIM; kk += 32) {
    gload_lds16(aptr + kk, asl);
    gload_lds16(bptr + kk, bsl);
    gload_lds16(bptr + kk + 64 * DIM, bsl + 64 * 32);
    __syncthreads();
    s16x8 af[4], bfr[2];
#pragma unroll
    for (int m = 0; m < 4; ++m)
      af[m] = *(const s16x8*)&As[(m * 16 + lr) * 32 + lg * 8];
#pragma unroll
    for (int n = 0; n < 2; ++n)
      bfr[n] = *(const s16x8*)&Bs[(w * 32 + n * 16 + lr) * 32 + lg * 8];
    if (isV) {
#pragma unroll
      for (int m = 0; m < 4; ++m)
#pragma unroll
        for (int n = 0; n < 2; ++n)
          acc[m][n] = __builtin_amdgcn_mfma_f32_16x16x32_bf16(af[m], bfr[n], acc[m][n], 0, 0, 0);
    } else {
#pragma unroll
      for (int m = 0; m < 4; ++m)
#pragma unroll
        for (int n = 0; n < 2; ++n)
          acc[m][n] = __builtin_amdgcn_mfma_f32_16x16x32_bf16(bfr[n], af[m], acc[m][n], 0, 0, 0);
    }
    __syncthreads();
  }

  if (!isV) {
    // C^T epilogue: acc[m][n][j] = C[x-row = bm*64+m*16+lr]
    //                              [W-col = bn*128+w*32+n*16+lg*4+j]
    const int row0x = bm * 64;
#pragma unroll
    for (int n = 0; n < 2; ++n) {
      const int colb = bn * 128 + w * 32 + n * 16 + lg * 4;   // 4-aligned
      const f32x4 bv4 = *(const f32x4*)&bias[colb];
      const int which = colb >> 10;                           // 0=Q, 1=K
      const int head = (colb & 1023) >> 6;
      const int d0 = colb & 63;                               // 4-aligned
      if (which == 0) {
        short* dst = Qb + head * (L_SEQ * HD);
#pragma unroll
        for (int m = 0; m < 4; ++m) {
          const int xrow = row0x + m * 16 + lr;
          s16x4 wv;
#pragma unroll
          for (int j = 0; j < 4; ++j) wv[j] = f2bf((acc[m][n][j] + bv4[j]) * QSCL);
          *(s16x4*)&dst[xrow * HD + d0] = wv;
        }
      } else {
        short* dst = Kf + head * (L_SEQ * HD);
        const int c = d0 >> 4, khi = (d0 >> 3) & 1, e0 = d0 & 7;  // e0 in {0,4}
#pragma unroll
        for (int m = 0; m < 4; ++m) {
          const int xrow = row0x + m * 16 + lr;
          const int p = xrow >> 5;
          const int lane = khi * 32 + (xrow & 31);
          s16x4 wv;
#pragma unroll
          for (int j = 0; j < 4; ++j) wv[j] = f2bf(acc[m][n][j] + bv4[j]);
          *(s16x4*)&dst[((p * 4 + c) * 64 + lane) * 8 + e0] = wv;
        }
      }
    }
  } else {
    // V normal epilogue -> frag-order store (layout as previous rounds)
#pragma unroll
    for (int n = 0; n < 2; ++n) {
      const int col = bn * 128 + w * 32 + n * 16 + lr;
      const float bv = bias[col];
      const int head = (col & 1023) >> 6;
      const int d = col & 63;
      const int dh = d >> 5;
      const int dq = d & 31;
      short* dst = Vf + head * (L_SEQ * HD);
#pragma unroll
      for (int m = 0; m < 4; ++m) {
        const int rowb = bm * 64 + m * 16 + lg * 4;
        const int tt = rowb >> 6;
        const int kc = (rowb >> 4) & 3;
        const int khi = (rowb >> 3) & 1;
        const int e0 = rowb & 7;
        s16x4 wv;
#pragma unroll
        for (int j = 0; j < 4; ++j) wv[j] = f2bf(acc[m][n][j] + bv);
        *(s16x4*)&dst[(((tt * 4 + kc) * 2 + dh) * 64 + khi * 32 + dq) * 8 + e0] = wv;
      }
    }
  }
}

// ---------------- out-proj GEMM: 64x64 tile, BK=32. Grid 1024, T1 remap. --------
__global__ __launch_bounds__(256) void gemm_out64(const short* __restrict__ A,
                                                  const short* __restrict__ B,
                                                  const float* __restrict__ bias,
                                                  float* __restrict__ C) {
  __shared__ __align__(16) short As[64 * 32];
  __shared__ __align__(16) short Bs[64 * 32];
  const int t = threadIdx.x;
  const int w = t >> 6, l = t & 63;
  const int wr = w >> 1, wc = w & 1;
  const int lr = l & 15, lg = l >> 4;
  const int bid = blockIdx.x;
  const int xcd = bid & 7;
  const int ii = bid >> 3;              // 0..127
  const int bm = xcd * 8 + (ii & 7);    // 0..63
  const int bn = ii >> 3;               // 0..15

  f32x4 acc[2][2];
#pragma unroll
  for (int m = 0; m < 2; ++m)
#pragma unroll
    for (int n = 0; n < 2; ++n) acc[m][n] = (f32x4)0.f;

  const short* aptr = A + (bm * 64 + (t >> 2)) * DIM + (t & 3) * 8;
  const short* bptr = B + (bn * 64 + (t >> 2)) * DIM + (t & 3) * 8;
  short* asl = &As[t * 8];
  short* bsl = &Bs[t * 8];

  for (int kk = 0; kk < DIM; kk += 32) {
    gload_lds16(aptr + kk, asl);
    gload_lds16(bptr + kk, bsl);
    __syncthreads();
    s16x8 af[2], bfr[2];
#pragma unroll
    for (int m = 0; m < 2; ++m)
      af[m] = *(const s16x8*)&As[(wr * 32 + m * 16 + lr) * 32 + lg * 8];
#pragma unroll
    for (int n = 0; n < 2; ++n)
      bfr[n] = *(const s16x8*)&Bs[(wc * 32 + n * 16 + lr) * 32 + lg * 8];
#pragma unroll
    for (int m = 0; m < 2; ++m)
#pragma unroll
      for (int n = 0; n < 2; ++n)
        acc[m][n] = __builtin_amdgcn_mfma_f32_16x16x32_bf16(af[m], bfr[n], acc[m][n], 0, 0, 0);
    __syncthreads();
  }

  const int row0 = bm * 64 + wr * 32;
  const int col0 = bn * 64 + wc * 32;
#pragma unroll
  for (int n = 0; n < 2; ++n) {
    const int col = col0 + n * 16 + lr;
    const float bv = bias[col];
#pragma unroll
    for (int m = 0; m < 2; ++m)
#pragma unroll
      for (int j = 0; j < 4; ++j) {
        const int row = row0 + m * 16 + lg * 4 + j;
        C[row * DIM + col] = acc[m][n][j] + bv;
      }
  }
}

// ---------------- Flash attention: QBLK=64, LDS-shared K/V (round-15, 53us) -----
__global__ __launch_bounds__(256, 4) void attn64(const short* __restrict__ Qb,
                                                 const short* __restrict__ Kf,
                                                 const short* __restrict__ Vf,
                                                 short* __restrict__ Ob) {
  __shared__ __align__(16) short KV[2][8192];  // 2 x 16KB: [Kev|Kod|Vev|Vod] x 4KB
  const int bid = blockIdx.x;
  const int xcd = bid & 7;
  const int i = bid >> 3;                       // 0..127
  const int head = (xcd << 1) | (i >> 6);       // 2 heads per XCD
  const int j = i & 63;
  const int qt = (j < 32) ? (63 - j) : (j - 32);  // balanced heavy/light per CU
  const int q0 = qt * 64;
  const int h = threadIdx.x >> 6;               // wave id 0..3
  const int l = threadIdx.x & 63;
  const int q = l & 31;
  const int hi = l >> 5;
  const int sb = h >> 1;                        // q-subtile 0/1
  const int p = h & 1;                          // kt parity

  const short* Qh = Qb + head * (L_SEQ * HD);
  const short* Kh = Kf + head * (L_SEQ * HD);
  const short* Vh = Vf + head * (L_SEQ * HD);
  const short* gKV = (h < 2) ? Kh : Vh;         // this wave's staging source

  s16x8 qf[4];
#pragma unroll
  for (int c = 0; c < 4; ++c)
    qf[c] = *(const s16x8*)&Qh[(q0 + sb * 32 + q) * HD + c * 16 + hi * 8];

  f32x16 o0 = (f32x16)0.f, o1 = (f32x16)0.f;
  f32x4 lvec = (f32x4)0.f;

  const int nr = qt + 1;                        // 64-key rounds

  // prologue: stage round 0 (wave h stages region h: kt = p of K or V)
  {
    const short* gsrc = gKV + p * 2048;
    short* lb = &KV[0][h * 2048];
#pragma unroll
    for (int c = 0; c < 4; ++c) gload_lds16(gsrc + c * 512 + l * 8, lb + c * 512);
  }
  __syncthreads();

  for (int r = 0; r < nr; ++r) {
    const int buf = r & 1;
    if (r + 1 < nr) {                           // stage next round into other buf
      const short* gsrc = gKV + (2 * (r + 1) + p) * 2048;
      short* lb = &KV[buf ^ 1][h * 2048];
#pragma unroll
      for (int c = 0; c < 4; ++c) gload_lds16(gsrc + c * 512 + l * 8, lb + c * 512);
    }

    const bool last = (r == nr - 1);
    if (!(h == 1 && last)) {                    // wave1's last tile fully masked
      const short* kb = &KV[buf][p * 2048];
      const short* vb = &KV[buf][(2 + p) * 2048];

      s16x8 kfr[4];
#pragma unroll
      for (int c = 0; c < 4; ++c)
        kfr[c] = *(const s16x8*)&kb[c * 512 + l * 8];

      f32x16 s = (f32x16)0.f;
      __builtin_amdgcn_s_setprio(1);
#pragma unroll
      for (int c = 0; c < 4; ++c)
        s = __builtin_amdgcn_mfma_f32_32x32x16_bf16(kfr[c], qf[c], s, 0, 0, 0);
      __builtin_amdgcn_s_setprio(0);

      // diagonal mask: wave0 (sbA, kt even) / wave3 (sbB, kt odd) on last round
      if (last && (h == 0 || h == 3)) {
        const int qrel = q - hi * 4;
#pragma unroll
        for (int rr = 0; rr < 16; ++rr) {
          const int koff = (rr & 3) + 8 * (rr >> 2);
          if (koff > qrel) s[rr] = -1e30f;
        }
      }

#pragma unroll
      for (int rr = 0; rr < 16; ++rr) s[rr] = exp2_fast(s[rr]);
#pragma unroll
      for (int rr = 0; rr < 16; ++rr) lvec[rr & 3] += s[rr];

#pragma unroll
      for (int cc = 0; cc < 2; ++cc) {
        const int roff = cc * 8;
        const unsigned A = cvt_pk_bf16(s[roff + 0], s[roff + 1]);
        const unsigned B = cvt_pk_bf16(s[roff + 2], s[roff + 3]);
        const unsigned C = cvt_pk_bf16(s[roff + 4], s[roff + 5]);
        const unsigned D = cvt_pk_bf16(s[roff + 6], s[roff + 7]);
        u32x4 pw;
#if HAVE_PLSWAP
        const u32x2 r02 = __builtin_amdgcn_permlane32_swap(A, C, false, false);
        const u32x2 r13 = __builtin_amdgcn_permlane32_swap(B, D, false, false);
        pw[0] = r02[0]; pw[1] = r13[0]; pw[2] = r02[1]; pw[3] = r13[1];
#else
        const unsigned sA = (unsigned)__shfl_xor((int)A, 32, 64);
        const unsigned sB = (unsigned)__shfl_xor((int)B, 32, 64);
        const unsigned sC = (unsigned)__shfl_xor((int)C, 32, 64);
        const unsigned sD = (unsigned)__shfl_xor((int)D, 32, 64);
        pw[0] = hi ? sC : A; pw[1] = hi ? sD : B;
        pw[2] = hi ? C : sA; pw[3] = hi ? D : sB;
#endif
        const s16x8 pf = __builtin_bit_cast(s16x8, pw);
        const s16x8 vf0 = *(const s16x8*)&vb[(cc * 2 + 0) * 512 + l * 8];
        const s16x8 vf1 = *(const s16x8*)&vb[(cc * 2 + 1) * 512 + l * 8];
        __builtin_amdgcn_s_setprio(1);
        o0 = __builtin_amdgcn_mfma_f32_32x32x16_bf16(vf0, pf, o0, 0, 0, 0);
        o1 = __builtin_amdgcn_mfma_f32_32x32x16_bf16(vf1, pf, o1, 0, 0, 0);
        __builtin_amdgcn_s_setprio(0);
      }
    }
    __syncthreads();   // drains this wave's gloads (vmcnt0) + orders buffers
  }

  // per-wave denominator: 4 chains + cross-half exchange
  float lsum = (lvec[0] + lvec[1]) + (lvec[2] + lvec[3]);
  lsum += __shfl_xor(lsum, 32, 64);

  // ---- pairwise merge (same m=0 reference -> plain add). Alias staging LDS. ----
  unsigned* Ms = (unsigned*)&KV[0][0];          // [2][64][17]
  if (p == 1) {                                 // waves 1,3 write partials
    unsigned* st = Ms + (sb * 64 + l) * 17;
#pragma unroll
    for (int w2 = 0; w2 < 8; ++w2) st[w2]     = cvt_pk_bf16(o0[2 * w2], o0[2 * w2 + 1]);
#pragma unroll
    for (int w2 = 0; w2 < 8; ++w2) st[8 + w2] = cvt_pk_bf16(o1[2 * w2], o1[2 * w2 + 1]);
    st[16] = __builtin_bit_cast(unsigned, lsum);
  }
  __syncthreads();
  if (p == 0) {                                 // waves 0,2 combine & write
    const unsigned* st = Ms + (sb * 64 + l) * 17;
    lsum += __builtin_bit_cast(float, st[16]);
#pragma unroll
    for (int w2 = 0; w2 < 8; ++w2) {
      const unsigned ua = st[w2];
      o0[2 * w2]     += __builtin_bit_cast(float, ua << 16);
      o0[2 * w2 + 1] += __builtin_bit_cast(float, ua & 0xffff0000u);
      const unsigned ub = st[8 + w2];
      o1[2 * w2]     += __builtin_bit_cast(float, ub << 16);
      o1[2 * w2 + 1] += __builtin_bit_cast(float, ub & 0xffff0000u);
    }
    const float inv = 1.f / lsum;
    const int orow = q0 + sb * 32 + q;
#pragma unroll
    for (int dh = 0; dh < 2; ++dh) {
#pragma unroll
      for (int tq = 0; tq < 4; ++tq) {
        s16x4 wv;
#pragma unroll
        for (int jj = 0; jj < 4; ++jj) {
          const int rr = tq * 4 + jj;
          const float ov = (dh == 0) ? o0[rr] : o1[rr];
          wv[jj] = f2bf(ov * inv);
        }
        *(s16x4*)&Ob[orow * DIM + head * HD + dh * 32 + tq * 8 + hi * 4] = wv;
      }
    }
  }
}

// ---------------- launch ----------------
extern "C" void kernel_launch(void* const* d_in, const int* in_sizes, int n_in,
                              void* d_out, int out_size, void* d_ws, size_t ws_size,
                              hipStream_t stream) {
  const float* x    = (const float*)d_in[0];
  const float* Wqkv = (const float*)d_in[1];
  const float* bqkv = (const float*)d_in[2];
  const float* Wout = (const float*)d_in[3];
  const float* bout = (const float*)d_in[4];
  float* out = (float*)d_out;

  char* ws = (char*)d_ws;
  short* xb    = (short*)(ws);                    // 8 MB  [L][D] bf16
  short* wqkvb = (short*)(ws + (8u  << 20));      // 6 MB  [3D][D] bf16
  short* woutb = (short*)(ws + (14u << 20));      // 2 MB  [D][D] bf16
  short* Qb    = (short*)(ws + (16u << 20));      // 8 MB  [NH][L][64] (pre-scaled)
  short* Kf    = (short*)(ws + (24u << 20));      // 8 MB  frag-order K
  short* Vf    = (short*)(ws + (32u << 20));      // 8 MB  frag-order V
  short* Ob    = (short*)(ws + (40u << 20));      // 8 MB  [L][D] bf16

  cvt_all<<<(CVT_N1 + CVT_N2 + CVT_N3) / 256, 256, 0, stream>>>(x, Wqkv, Wout, xb, wqkvb, woutb);

  gemm_qkv64<<<1536, 256, 0, stream>>>(xb, wqkvb, bqkv, Qb, Kf, Vf);
  attn64<<<1024, 256, 0, stream>>>(Qb, Kf, Vf, Ob);
  gemm_out64<<<1024, 256, 0, stream>>>(Ob, woutb, bout, out);
}